// Round 4
// baseline (745.320 us; speedup 1.0000x reference)
//
#include <hip/hip_runtime.h>
#include <hip/hip_bf16.h>

// DILATE loss: fused soft-DTW fwd+bwd, wave-skewed superstep pipeline.
// Round 4: TWO samples per 512-thread block (two 4-wave groups in lockstep)
// so each SIMD hosts 2 independent waves -> latency hiding; fwd softmin via
// min3/med3/max3 (min term's exp == 1) -> 2 exps instead of 3.
// Scaled domain: R'' = R * (100/ln2) so softmin/weights use raw exp2/log2.

#define NSEQ 512
#define K2   144.269504088896f      // (1/gamma)*log2(e) = 100/ln2
#define SC   0.006931471805599453f  // inverse scale = ln2/100
#define BIGV 1e10f
#define NEGV -1e30f
#define ALPHA 0.5f

#define WST   640                     // stored local diagonal steps per wave
#define SLAB2 ((size_t)4 * WST * 64)  // float2 elements per sample

__global__ __launch_bounds__(512) void dilate_fused(
    const float* __restrict__ outp, const float* __restrict__ targ,
    float2* __restrict__ slabAll, float* __restrict__ vals,
    float* __restrict__ svals, int kbase, int kend)
{
    const int tid = threadIdx.x;
    const int g   = tid >> 8;                // sample group (0/1)
    const int lt  = tid & 255;               // thread id within group
    const int w   = lt >> 6;                 // wave within group (0..3)
    const int l   = tid & 63;
    const int i0  = 128 * w + 2 * l;         // lane owns rows i0, i0+1
    const bool lane0 = (l == 0), lane63 = (l == 63);

    int ks = kbase + 2 * blockIdx.x + g;
    const bool active = (ks < kend);
    if (!active) ks = kbase + 2 * blockIdx.x;          // alias group 0's sample
    const int slabidx = 2 * blockIdx.x + (active ? g : 0);

    __shared__ float o_pad[2][644];   // o[-1..642] at [j+1], pads = 0
    __shared__ float t_sh[2][516];
    __shared__ float Rbf[2][3][644];  // fwd boundary rows by column (col c at [c+1])
    __shared__ float Rbb[2][3][644];  // bwd boundary R
    __shared__ float Ebb[2][3][644];  // bwd boundary E
    __shared__ float dummyF[644];     // virtual row -1: [0]=0 (R[-1,-1]), else BIG
    __shared__ float dummyZ[644];     // zeros (virtual row 512)
    __shared__ float red[2][4];

    for (int q = tid; q < 644; q += 512) { dummyF[q] = BIGV; dummyZ[q] = 0.f; }
    for (int q = lt; q < 644; q += 256) o_pad[g][q] = 0.f;
    for (int q = lt; q < 516; q += 256) t_sh[g][q] = 0.f;
    __syncthreads();
    if (lt == 0) {
        if (g == 0) dummyF[0] = 0.f;                   // virtual R[-1,-1] = 0
        Rbf[g][0][0] = BIGV; Rbf[g][1][0] = BIGV; Rbf[g][2][0] = BIGV;
        Rbb[g][0][0] = NEGV; Rbb[g][1][0] = NEGV; Rbb[g][2][0] = NEGV;
        Ebb[g][0][0] = 0.f;  Ebb[g][1][0] = 0.f;  Ebb[g][2][0] = 0.f;
    }
    for (int q = lt; q < NSEQ; q += 256) {
        o_pad[g][1 + q] = outp[(size_t)ks * NSEQ + q];
        t_sh[g][q]      = targ[(size_t)ks * NSEQ + q];
    }
    __syncthreads();

    const float t0 = t_sh[g][i0], t1 = t_sh[g][i0 + 1], t2 = t_sh[g][i0 + 2];

    const float* RbfR = (w == 0) ? dummyF : Rbf[g][w - 1];
    float*       RbfW = Rbf[g][w < 3 ? w : 2];         // guarded by (w<3)
    const float* RbbR = (w == 3) ? dummyZ : Rbb[g][w];
    const float* EbbR = (w == 3) ? dummyZ : Ebb[g][w];
    float*       RbbW = Rbb[g][(w > 0 ? w : 1) - 1];   // guarded by (w>0)
    float*       EbbW = Ebb[g][(w > 0 ? w : 1) - 1];

    float2* __restrict__ sp = slabAll + (size_t)slabidx * SLAB2
                              + (size_t)(w * WST) * 64 + l;

    // ---------------- forward ----------------
    float rp1_0 = BIGV, rp1_1 = BIGV, rp2_0 = BIGV, rp2_1 = BIGV;
    float rfinal = BIGV;

    for (int ss = 0; ss < 19; ++ss) {
        const int mw = ss - 3 * w;               // wave-local window
        if (0 <= mw && mw < 10) {
            const int tb  = (mw + 2 * w) * 64;   // global diag base
            const int tl0 = mw * 64;             // local stored index base
            int j0 = tb - i0;
            #pragma unroll 8
            for (int u = 0; u < 64; ++u, ++j0) {
                const int ob = (j0 > 0) ? j0 : 0;
                const float oj  = o_pad[g][ob + 1];  // o[j0]
                const float ojm = o_pad[g][ob];      // o[j0-1]
                const float bdA = RbfR[ob + 1];      // R[i0-1, j0]
                const float bdB = RbfR[ob];          // R[i0-1, j0-1]
                const float sA = __shfl_up(rp1_1, 1);
                const float sB = __shfl_up(rp2_1, 1);
                const float a0 = lane0 ? bdA : sA;
                const float b0 = lane0 ? bdB : sB;
                const float c0 = rp1_0;
                // cell r=0: (i0, j0).  softmin = mn - log2(1 + 2^(mn-md) + 2^(mn-mx))
                float mn0 = fminf(fminf(a0, b0), c0);
                float mx0 = fmaxf(fmaxf(a0, b0), c0);
                float md0 = __builtin_amdgcn_fmed3f(a0, b0, c0);
                float s0 = 1.0f + __builtin_exp2f(mn0 - md0) + __builtin_exp2f(mn0 - mx0);
                float sm0 = mn0 - __builtin_log2f(s0);
                float dv0 = t0 - oj;
                float r0v = fmaf(dv0 * dv0, K2, sm0);
                // cell r=1: (i0+1, j0-1) — uses only pre-rotation registers
                float mn1 = fminf(fminf(rp1_0, rp2_0), rp1_1);
                float mx1 = fmaxf(fmaxf(rp1_0, rp2_0), rp1_1);
                float md1 = __builtin_amdgcn_fmed3f(rp1_0, rp2_0, rp1_1);
                float s1 = 1.0f + __builtin_exp2f(mn1 - md1) + __builtin_exp2f(mn1 - mx1);
                float sm1 = mn1 - __builtin_log2f(s1);
                float dv1 = t1 - ojm;
                float r1v = fmaf(dv1 * dv1, K2, sm1);
                const bool act0 = ((unsigned)j0 < 512u);
                const bool act1 = ((unsigned)(j0 - 1) < 512u);
                const float r0n = act0 ? r0v : BIGV;
                const float r1n = act1 ? r1v : BIGV;
                rp2_0 = rp1_0; rp1_0 = r0n;
                rp2_1 = rp1_1; rp1_1 = r1n;
                float2 st; st.x = act0 ? r0v : NEGV; st.y = act1 ? r1v : NEGV;
                sp[(size_t)(tl0 + u) * 64] = st;
                if (lane63 && w < 3 && act1) RbfW[j0] = r1n;  // col j0-1 at [j0]
                if (u == 62 && mw == 9) rfinal = r1v;         // (511,511) on wave 3
            }
        }
        asm volatile("s_waitcnt lgkmcnt(0)\n\ts_barrier" ::: "memory");
    }

    // phase transition: own-thread store->load ordering for the slab
    asm volatile("s_waitcnt vmcnt(0)" ::: "memory");
    if (w == 3 && lane63 && active) vals[ks] = rfinal * SC;

    // ---------------- backward ----------------
    float ep1_0 = 0.f, ep1_1 = 0.f, ep2_0 = 0.f, ep2_1 = 0.f;
    rp1_0 = NEGV; rp1_1 = NEGV; rp2_0 = NEGV; rp2_1 = NEGV;
    float acc = 0.f;

    const int j0s = 639 - 2 * l;                 // j0 at first bwd step
    float ocar = o_pad[g][j0s + 2];              // o[j0s+1]
    const float otmp = o_pad[g][j0s + 1];        // o[j0s]
    float dB0 = (t1 - ocar) * (t1 - ocar);       // carry: (t1 - o[j0+1])^2
    float dB1 = (t2 - otmp) * (t2 - otmp);       // carry: (t2 - o[j0])^2

    float2 ring[8];
    #pragma unroll
    for (int p = 0; p < 8; ++p) ring[(639 - p) & 7] = sp[(size_t)(639 - p) * 64];

    for (int ssb = 0; ssb < 19; ++ssb) {
        const int mw = 18 - 3 * w - ssb;
        if (0 <= mw && mw < 10) {
            const int tb  = (mw + 2 * w) * 64;
            const int tl0 = mw * 64;
            float dif0 = (float)(2 * i0 - (tb + 63));   // i0 - j0 at u=0
            int j0 = tb + 63 - i0;
            for (int ub = 0; ub < 8; ++ub) {
                #pragma unroll
                for (int uq = 0; uq < 8; ++uq) {
                    const int u = ub * 8 + uq;
                    const int tl = tl0 + 63 - u;
                    const int slot = 7 - uq;             // == tl & 7
                    const float2 rc = ring[slot];        // R(t) rows i0, i0+1
                    {   // prefetch t-8
                        int tln = tl - 8; if (tln < 0) tln = 0;
                        ring[slot] = sp[(size_t)tln * 64];
                    }
                    const int ob = (j0 > 0) ? j0 : 0;
                    const float ojm = o_pad[g][ob];      // o[j0-1]
                    const float oj  = o_pad[g][ob + 1];  // o[j0]
                    const float bR0 = RbbR[ob];          // R[128(w+1), j0-1]
                    const float bR1 = RbbR[ob + 1];      // R[128(w+1), j0]
                    const float bE0 = EbbR[ob];
                    const float bE1 = EbbR[ob + 1];
                    const float shR1 = __shfl_down(rp1_0, 1);
                    const float shR2 = __shfl_down(rp2_0, 1);
                    const float shE1 = __shfl_down(ep1_0, 1);
                    const float shE2 = __shfl_down(ep2_0, 1);
                    const float rA1 = lane63 ? bR0 : shR1;  // R[i0+2, j0-1] (t+1)
                    const float rB1 = lane63 ? bR1 : shR2;  // R[i0+2, j0]   (t+2)
                    const float eA1 = lane63 ? bE0 : shE1;
                    const float eB1 = lane63 ? bE1 : shE2;
                    const float rij0 = rc.x, rij1 = rc.y;
                    const float dvA0 = t1 - oj;  const float dA0 = dvA0 * dvA0;
                    const float dvC0 = t0 - ocar; const float dC0 = dvC0 * dvC0;
                    const float dvA1 = t2 - ojm; const float dA1 = dvA1 * dvA1;
                    // cell r=0 (i0, j0): children (i0+1,j0),(i0,j0+1),(i0+1,j0+1)
                    float e0 = ep1_1 * __builtin_exp2f(fmaf(dA0, -K2, rp1_1 - rij0));
                    e0 = fmaf(ep1_0, __builtin_exp2f(fmaf(dC0, -K2, rp1_0 - rij0)), e0);
                    e0 = fmaf(ep2_1, __builtin_exp2f(fmaf(dB0, -K2, rp2_1 - rij0)), e0);
                    // cell r=1 (i0+1, j0-1): children (i0+2,j0-1),(i0+1,j0),(i0+2,j0)
                    float e1 = eA1 * __builtin_exp2f(fmaf(dA1, -K2, rA1 - rij1));
                    e1 = fmaf(ep1_1, __builtin_exp2f(fmaf(dA0, -K2, rp1_1 - rij1)), e1);
                    e1 = fmaf(eB1, __builtin_exp2f(fmaf(dB1, -K2, rB1 - rij1)), e1);
                    const bool act0 = ((unsigned)j0 < 512u);
                    const bool act1 = ((unsigned)(j0 - 1) < 512u);
                    float E0 = act0 ? e0 : 0.f;
                    float E1 = act1 ? e1 : 0.f;
                    if (u == 1 && mw == 9 && w == 3 && lane63) E1 = 1.0f; // seed (511,511)
                    const float d1f = dif0 + 2.0f;
                    acc = fmaf(E0 * dif0, dif0, acc);
                    acc = fmaf(E1 * d1f, d1f, acc);
                    if (lane0 && w > 0) { RbbW[j0 + 1] = rij0; EbbW[j0 + 1] = E0; }
                    rp2_0 = rp1_0; rp1_0 = rij0;
                    rp2_1 = rp1_1; rp1_1 = rij1;
                    ep2_0 = ep1_0; ep1_0 = E0;
                    ep2_1 = ep1_1; ep1_1 = E1;
                    dB0 = dA0; dB1 = dA1;
                    ocar = oj;
                    dif0 += 1.0f;
                    --j0;
                }
            }
        }
        asm volatile("s_waitcnt lgkmcnt(0)\n\ts_barrier" ::: "memory");
    }

    for (int off = 32; off; off >>= 1) acc += __shfl_down(acc, off);
    if (lane0) red[g][w] = acc;
    __syncthreads();
    if (lt == 0 && active)
        svals[ks] = red[g][0] + red[g][1] + red[g][2] + red[g][3];
}

__global__ void finalize_kernel(const float* __restrict__ vals,
                                const float* __restrict__ svals,
                                float* __restrict__ out, int B) {
    int t = threadIdx.x;
    float v = 0.0f, s = 0.0f;
    for (int q = t; q < B; q += 64) { v += vals[q]; s += svals[q]; }
    for (int off = 32; off; off >>= 1) { v += __shfl_down(v, off); s += __shfl_down(s, off); }
    if (t == 0) {
        float loss_shape = v / (float)B;
        float loss_temporal = (s / (float)B) / ((float)NSEQ * (float)NSEQ);
        out[0] = ALPHA * loss_shape + (1.0f - ALPHA) * loss_temporal;
    }
}

extern "C" void kernel_launch(void* const* d_in, const int* in_sizes, int n_in,
                              void* d_out, int out_size, void* d_ws, size_t ws_size,
                              hipStream_t stream) {
    const float* outputs = (const float*)d_in[0];
    const float* targets = (const float*)d_in[1];
    const int B = in_sizes[0] / NSEQ;    // 64

    float* vals  = (float*)d_ws;
    float* svals = vals + 128;
    float2* slab = (float2*)((char*)d_ws + 1024);

    const size_t slab_bytes = SLAB2 * sizeof(float2);   // ~1.31 MB/sample
    size_t avail = (ws_size > 1024) ? (ws_size - 1024) / slab_bytes : 0;
    int G = (int)((avail < (size_t)B) ? avail : (size_t)B);
    if (G >= 2) G &= ~1;                 // even chunk so blocks carry 2 samples
    if (G < 1) G = 1;

    for (int kb = 0; kb < B; kb += G) {
        int gcnt = (B - kb < G) ? (B - kb) : G;
        int nblk = (gcnt + 1) / 2;
        dilate_fused<<<dim3(nblk), dim3(512), 0, stream>>>(
            outputs, targets, slab, vals, svals, kb, kb + gcnt);
    }
    finalize_kernel<<<dim3(1), dim3(64), 0, stream>>>(vals, svals, (float*)d_out, B);
}